// Round 19
// baseline (146.100 us; speedup 1.0000x reference)
//
#include <hip/hip_runtime.h>
#include <math.h>

// Problem constants (b=8, c=2048, e=64, h=8)
#define NTOK 16384
#define EDIM 64
#define HHE  512   // h*e
#define TPB  16    // tokens per block
#define TOKPAD 260 // half2 slots per token row: 256 + 4 pad (16B-aligned rows)

typedef _Float16 half8 __attribute__((ext_vector_type(8)));   // MFMA operand type
typedef __fp16   half2v __attribute__((ext_vector_type(2)));  // builtin V2h type
typedef _Float16 f16x2 __attribute__((ext_vector_type(2)));
typedef float    floatx4 __attribute__((ext_vector_type(4)));

__device__ __forceinline__ half8 cvt8(const float4 a, const float4 b) {
    half8 h;
    h[0] = (_Float16)a.x; h[1] = (_Float16)a.y;
    h[2] = (_Float16)a.z; h[3] = (_Float16)a.w;
    h[4] = (_Float16)b.x; h[5] = (_Float16)b.y;
    h[6] = (_Float16)b.z; h[7] = (_Float16)b.w;
    return h;
}

// fp32 += half2 . half2 (v_dot2_f32_f16)
__device__ __forceinline__ float dot2(half2v a, half2v b, float c) {
#if __has_builtin(__builtin_amdgcn_fdot2)
    return __builtin_amdgcn_fdot2(a, b, c, false);
#else
    return fmaf((float)a[0], (float)b[0], fmaf((float)a[1], (float)b[1], c));
#endif
}
__device__ __forceinline__ half2v pk(float x, float y) {
    return __builtin_amdgcn_cvt_pkrtz(x, y);   // v_cvt_pkrtz_f16_f32 (V2h)
}
union h2u { half2v h; f16x2 f; unsigned int u; };
union uqu { half8 h8; half2v h2[4]; };

// ---- FORCED packed-fp16 VOP3P ops on 32-bit pair registers (inline asm;
// hipcc does not form these from vector types — proven R21/R22 counters).
__device__ __forceinline__ unsigned pka16(unsigned a, unsigned b) {
    unsigned d;
    asm("v_pk_add_f16 %0, %1, %2" : "=v"(d) : "v"(a), "v"(b));
    return d;
}
__device__ __forceinline__ unsigned pkmax16(unsigned a, unsigned b) {
    unsigned d;
    asm("v_pk_max_f16 %0, %1, %2" : "=v"(d) : "v"(a), "v"(b));
    return d;
}
__device__ __forceinline__ unsigned pkmul16(unsigned a, unsigned b) {
    unsigned d;
    asm("v_pk_mul_f16 %0, %1, %2" : "=v"(d) : "v"(a), "v"(b));
    return d;
}
__device__ __forceinline__ unsigned pkrelu16(unsigned x, unsigned z0) {
    return pkmax16(x, z0);   // clamp pair to [0,inf); 0u = +0|+0 fp16 pair
}
__device__ __forceinline__ float dot2u(unsigned a, unsigned b, float c) {
    h2u ua, ub; ua.u = a; ub.u = b;
    return dot2(ua.h, ub.h, c);
}

__device__ __forceinline__ float pgen(float z, float inv) {
    return z > 0.0f ? exp2f(inv * log2f(fmaxf(z, 1e-30f))) : 0.0f;
}

// ---------------------------------------------------------------------------
// Kernel 0: fp32 -> fp16 (RTN cast) for the 4 weight matrices only.
// Wq pre-scaled by (alpha-1)/sqrt(e) so the score scale vanishes downstream.
// ---------------------------------------------------------------------------
__global__ __launch_bounds__(256) void cvt_fp16_kernel(
    const float* __restrict__ Wk, const float* __restrict__ Wq,
    const float* __restrict__ Wv, const float* __restrict__ Wu,
    __fp16* __restrict__ wkh, __fp16* __restrict__ wqh,
    __fp16* __restrict__ wvh, __fp16* __restrict__ wuh,
    const float* alpha_p)
{
    const int z = blockIdx.y;
    const float* src; __fp16* dst;
    float s = 1.0f;
    if      (z == 0) { src = Wk; dst = wkh; }
    else if (z == 1) { src = Wq; dst = wqh; s = (alpha_p[0] - 1.0f) * 0.125f; }
    else if (z == 2) { src = Wv; dst = wvh; }
    else             { src = Wu; dst = wuh; }
    const int idx = (blockIdx.x * 256 + threadIdx.x) * 8;
    float4 a = *(const float4*)(src + idx);
    float4 b = *(const float4*)(src + idx + 4);
    a.x *= s; a.y *= s; a.z *= s; a.w *= s;
    b.x *= s; b.y *= s; b.z *= s; b.w *= s;
    *(half8*)(dst + idx) = cvt8(a, b);
}

// ---------------------------------------------------------------------------
// Kernel 1: FULLY FUSED qkv + entmax-attention + output projection.
// R28: launch_bounds REMOVED (was (256,4)/(256,3)). R27 proved the cap
// value is a codegen no-op: (256,3)'s 170-reg budget reproduced R26's
// binary bit-for-bit (VGPR 52, WRITE 20.5MB, FETCH 11.5MB). So the
// remaining lever is the bound's PRESENCE. R23 (no bounds) allocated
// 84 VGPR with CLEAN traffic (3.3/4.1MB) — if the scratch traffic is
// bound-induced, removing the bound restores it while the R26
// structure (33KB LDS, running pk_max, acc[4] halves, light cold
// path) keeps 4-blocks/CU LDS-feasible and ~92 combined regs.
// ---------------------------------------------------------------------------
__global__ __launch_bounds__(256) void qkv_attn_out_kernel(
    const float* __restrict__ x,
    const __fp16* __restrict__ wkh, const float* __restrict__ bk,
    const __fp16* __restrict__ wqh, const float* __restrict__ bq,
    const __fp16* __restrict__ wvh, const float* __restrict__ bv,
    const __fp16* __restrict__ wuh, const float* __restrict__ bu,
    float* __restrict__ out, const float* alpha_p)
{
    __shared__ __align__(16) half2v bufA[TPB * TOKPAD];  // q -> v overlay
    __shared__ __align__(16) half2v kT[TPB * TOKPAD];    // k -> res overlay

    const int tid  = threadIdx.x;
    const int lane = tid & 63;
    const int w    = tid >> 6;
    const int tok0 = blockIdx.x * TPB;

    const int m    = lane & 15;            // token (B row / MFMA D col)
    const int quad = lane >> 4;

    const float am1   = alpha_p[0] - 1.0f;
    const float s_q   = am1 * 0.125f;      // matches cvt kernel's Wq scale

    // ---- x B-fragments: fp32 load + RTN cast
    const float* xrow = x + (size_t)(tok0 + m) * EDIM + quad * 8;
    half8 bfr[2];
    {
        const float4 a0 = *(const float4*)(xrow);
        const float4 a1 = *(const float4*)(xrow + 4);
        const float4 a2 = *(const float4*)(xrow + 32);
        const float4 a3 = *(const float4*)(xrow + 36);
        bfr[0] = cvt8(a0, a1);
        bfr[1] = cvt8(a2, a3);
    }

    // ---- Phase A: produce k (units 0-3) and q (units 4-7); 2 units/wave.
    #pragma unroll
    for (int uu = 0; uu < 2; ++uu) {
        const int unit = w * 2 + uu;
        const int isq  = unit >> 2;            // 0 = k, 1 = q
        const int col0 = (unit & 3) * 128;
        const __fp16* W   = isq ? wqh : wkh;
        const float* bias = isq ? bq : bk;
        half2v* dstT      = isq ? bufA : kT;
        const float bs    = isq ? s_q : 1.0f;

        #pragma unroll
        for (int ct = 0; ct < 8; ++ct) {
            const int n = col0 + ct * 16 + m;
            const int grow = (n & 7) * 64 + (n >> 3);   // permuted W row (q/k)
            const __fp16* wrow = W + (size_t)grow * EDIM + quad * 8;
            floatx4 acc = (floatx4){0.f, 0.f, 0.f, 0.f};
            #pragma unroll
            for (int kc = 0; kc < 2; ++kc) {
                const half8 af = *(const half8*)(wrow + kc * 32);
                acc = __builtin_amdgcn_mfma_f32_16x16x32_f16(af, bfr[kc], acc, 0, 0, 0);
            }
            // lane's 4 regs = D rows quad*4+0..3, D col = m (token)
            // output rows g(n'): h = 4*(quad&1)+reg, j = col0/8+ct*2+(quad>>1)
            const int hbase = 4 * (quad & 1);
            const int j     = (col0 >> 3) + ct * 2 + (quad >> 1);
            float o0 = fmaf(bias[(hbase + 0) * 64 + j], bs, acc[0]);
            float o1 = fmaf(bias[(hbase + 1) * 64 + j], bs, acc[1]);
            float o2 = fmaf(bias[(hbase + 2) * 64 + j], bs, acc[2]);
            float o3 = fmaf(bias[(hbase + 3) * 64 + j], bs, acc[3]);
            h2u p0, p1;
            p0.h = pk(o0, o1);
            p1.h = pk(o2, o3);
            uint2 st; st.x = p0.u; st.y = p1.u;
            *(uint2*)&dstT[m * TOKPAD + j * 4 + 2 * (quad & 1)] = st;
        }
    }
    __syncthreads();   // #1: q,k fully written

    // ---- hoist this wave's 4 private q rows to registers (bufA dies after)
    uqu uqAll[4];
    #pragma unroll
    for (int i = 0; i < 4; ++i)
        uqAll[i].h8 = *(const half8*)&bufA[(w * 4 + i) * TOKPAD + lane * 4];
    __syncthreads();   // #2: all q reads complete before v overwrites bufA

    // ---- Phase B: produce v into bufA; 1 unit/wave (col0 = w*128)
    {
        const int col0 = w * 128;
        #pragma unroll
        for (int ct = 0; ct < 8; ++ct) {
            const int n = col0 + ct * 16 + m;
            const __fp16* wrow = wvh + (size_t)n * EDIM + quad * 8;  // natural row
            floatx4 acc = (floatx4){0.f, 0.f, 0.f, 0.f};
            #pragma unroll
            for (int kc = 0; kc < 2; ++kc) {
                const half8 af = *(const half8*)(wrow + kc * 32);
                acc = __builtin_amdgcn_mfma_f32_16x16x32_f16(af, bfr[kc], acc, 0, 0, 0);
            }
            // natural: cols nn..nn+3 = v[h][jj..jj+3]
            const int nn = col0 + ct * 16 + quad * 4;
            const int h  = nn >> 6;
            const int jj = nn & 63;
            const float4 b4 = *(const float4*)&bv[nn];
            h2u p0, p1;
            p0.h = pk(acc[0] + b4.x, acc[1] + b4.y);
            p1.h = pk(acc[2] + b4.z, acc[3] + b4.w);
            uint2 st; st.x = p0.u; st.y = p1.u;
            *(uint2*)&bufA[m * TOKPAD + h * 32 + (jj >> 1)] = st;
        }
    }
    __syncthreads();   // #3: v ready

    __fp16* resL = (__fp16*)kT;            // res overlay: kT rows are wave-private

    // ---- consumer: each wave runs 4 tokens serially
    #pragma unroll
    for (int i = 0; i < 4; ++i) {
        const int t = w * 4 + i;
        const uqu uq = uqAll[i];

        float inv_sum;
        // QK scores as fp16 pairs; reused in place as p^2 after the final
        // pass. Max tracked as a RUNNING pk_max inside the dot loop.
        unsigned rowh[32];

        if (am1 == 0.5f) {
            // ---- QK dot row -> fp16 pairs + running max
            unsigned runmax = 0u;
            #pragma unroll
            for (int j = 0; j < 64; j += 2) {
                uqu u0, u1;
                u0.h8 = *(const half8*)&kT[t * TOKPAD + j * 4];        // broadcast b128
                u1.h8 = *(const half8*)&kT[t * TOKPAD + (j + 1) * 4];
                float d0 = dot2(uq.h2[0], u0.h2[0], 0.0f);
                float d1 = dot2(uq.h2[0], u1.h2[0], 0.0f);
                d0 = dot2(uq.h2[1], u0.h2[1], d0);
                d1 = dot2(uq.h2[1], u1.h2[1], d1);
                d0 = dot2(uq.h2[2], u0.h2[2], d0);
                d1 = dot2(uq.h2[2], u1.h2[2], d1);
                d0 = dot2(uq.h2[3], u0.h2[3], d0);
                d1 = dot2(uq.h2[3], u1.h2[3], d1);
                h2u c; c.h = pk(d0, d1);
                rowh[j >> 1] = c.u;
                runmax = (j == 0) ? c.u : pkmax16(runmax, c.u);  // compile-time branch
            }
            h2u mu; mu.u = runmax;
            const float mx = fmaxf((float)mu.f[0], (float)mu.f[1]);

            float tau_lo = mx - 1.0f;                     // f(tau_lo) >= 0 provably
            float dm = 1.0f - exp2f(-6.0f * am1);         // tau_hi - tau_lo
            const unsigned z0 = 0u;                       // +0|+0 fp16 pair
            const half2v one2 = pk(1.0f, 1.0f);

            // ---- 6 bisection steps, forced packed fp16 + dot2 f-sums
            #pragma unroll
            for (int it = 0; it < 6; ++it) {
                dm *= 0.5f;
                const float tau_m = tau_lo + dm;
                h2u ntc; ntc.h = pk(-tau_m, -tau_m);
                const unsigned nt = ntc.u;
                float f0 = -1.0f, f1 = 0.0f, f2 = 0.0f, f3 = 0.0f;
                #pragma unroll
                for (int jj = 0; jj < 32; jj += 4) {
                    const unsigned a0 = pkrelu16(pka16(rowh[jj + 0], nt), z0);
                    const unsigned a1 = pkrelu16(pka16(rowh[jj + 1], nt), z0);
                    const unsigned a2 = pkrelu16(pka16(rowh[jj + 2], nt), z0);
                    const unsigned a3 = pkrelu16(pka16(rowh[jj + 3], nt), z0);
                    f0 = dot2u(a0, a0, f0);   // += a0lo^2 + a0hi^2 (one inst)
                    f1 = dot2u(a1, a1, f1);
                    f2 = dot2u(a2, a2, f2);
                    f3 = dot2u(a3, a3, f3);
                }
                const float f = (f0 + f1) + (f2 + f3);
                tau_lo = (f >= 0.0f) ? tau_m : tau_lo;
            }
            // ---- 2 guarded Newton steps, packed fp16 (f and s via dot2)
            float tau = tau_lo;
            #pragma unroll
            for (int it = 0; it < 2; ++it) {
                h2u ntc; ntc.h = pk(-tau, -tau);
                const unsigned nt = ntc.u;
                float f0 = -1.0f, f1 = 0.0f;
                float s0 = 0.0f, s1 = 0.0f;
                #pragma unroll
                for (int jj = 0; jj < 32; jj += 2) {
                    const unsigned a0 = pkrelu16(pka16(rowh[jj + 0], nt), z0);
                    const unsigned a1 = pkrelu16(pka16(rowh[jj + 1], nt), z0);
                    f0 = dot2u(a0, a0, f0);
                    f1 = dot2u(a1, a1, f1);
                    h2u ua0, ua1; ua0.u = a0; ua1.u = a1;
                    s0 = dot2(ua0.h, one2, s0);
                    s1 = dot2(ua1.h, one2, s1);
                }
                const float f = f0 + f1;
                const float s = (s0 + s1) + 1e-20f;
                tau = tau + fmaxf(f, 0.0f) * __builtin_amdgcn_rcpf(s + s);
            }
            // ---- final p: rowh[jj] <- a*a in fp16 (IN PLACE), sum via dot2
            {
                h2u ntc; ntc.h = pk(-tau, -tau);
                const unsigned nt = ntc.u;
                float s0 = 0.0f, s1 = 0.0f;
                #pragma unroll
                for (int jj = 0; jj < 32; jj += 2) {
                    const unsigned a0 = pkrelu16(pka16(rowh[jj + 0], nt), z0);
                    const unsigned a1 = pkrelu16(pka16(rowh[jj + 1], nt), z0);
                    s0 = dot2u(a0, a0, s0);
                    s1 = dot2u(a1, a1, s1);
                    rowh[jj + 0] = pkmul16(a0, a0);
                    rowh[jj + 1] = pkmul16(a1, a1);
                }
                inv_sum = __builtin_amdgcn_rcpf(s0 + s1);  // ~1ulp; under fp16 cast
            }
        } else {
            // faithful general-alpha fallback (alpha != 1.5; never taken in
            // this problem). REGISTER-LIGHT: recompute dots from LDS each
            // pass instead of keeping row[64] live — a fat cold path drives
            // the whole function's register allocation.
            const float inv = 1.0f / am1;
            float mx = -3.4e38f;
            for (int j = 0; j < 64; ++j) {
                uqu u0; u0.h8 = *(const half8*)&kT[t * TOKPAD + j * 4];
                float d = dot2(uq.h2[0], u0.h2[0], 0.0f);
                d = dot2(uq.h2[1], u0.h2[1], d);
                d = dot2(uq.h2[2], u0.h2[2], d);
                d = dot2(uq.h2[3], u0.h2[3], d);
                mx = fmaxf(mx, d);
            }
            float tau_lo = mx - 1.0f;
            float dm = (mx - exp2f(-6.0f * am1)) - tau_lo;
            float f_lo = -1.0f;
            for (int j = 0; j < 64; ++j) {
                uqu u0; u0.h8 = *(const half8*)&kT[t * TOKPAD + j * 4];
                float d = dot2(uq.h2[0], u0.h2[0], 0.0f);
                d = dot2(uq.h2[1], u0.h2[1], d);
                d = dot2(uq.h2[2], u0.h2[2], d);
                d = dot2(uq.h2[3], u0.h2[3], d);
                f_lo += pgen(d - tau_lo, inv);
            }
            float tau_m = tau_lo;
            for (int it = 0; it < 30; ++it) {
                dm *= 0.5f;
                tau_m = tau_lo + dm;
                float f = -1.0f;
                for (int j = 0; j < 64; ++j) {
                    uqu u0; u0.h8 = *(const half8*)&kT[t * TOKPAD + j * 4];
                    float d = dot2(uq.h2[0], u0.h2[0], 0.0f);
                    d = dot2(uq.h2[1], u0.h2[1], d);
                    d = dot2(uq.h2[2], u0.h2[2], d);
                    d = dot2(uq.h2[3], u0.h2[3], d);
                    f += pgen(d - tau_m, inv);
                }
                tau_lo = (f * f_lo >= 0.0f) ? tau_m : tau_lo;
            }
            float s = 0.0f;
            for (int j = 0; j < 64; j += 2) {
                uqu u0, u1;
                u0.h8 = *(const half8*)&kT[t * TOKPAD + j * 4];
                u1.h8 = *(const half8*)&kT[t * TOKPAD + (j + 1) * 4];
                float d0 = dot2(uq.h2[0], u0.h2[0], 0.0f);
                float d1 = dot2(uq.h2[0], u1.h2[0], 0.0f);
                d0 = dot2(uq.h2[1], u0.h2[1], d0);
                d1 = dot2(uq.h2[1], u1.h2[1], d1);
                d0 = dot2(uq.h2[2], u0.h2[2], d0);
                d1 = dot2(uq.h2[2], u1.h2[2], d1);
                d0 = dot2(uq.h2[3], u0.h2[3], d0);
                d1 = dot2(uq.h2[3], u1.h2[3], d1);
                const float p0 = pgen(d0 - tau_m, inv);
                const float p1 = pgen(d1 - tau_m, inv);
                s += p0 + p1;
                h2u c; c.h = pk(p0, p1);
                rowh[j >> 1] = c.u;
            }
            inv_sum = 1.0f / s;
        }

        // av: res[h][lane] = inv_sum * sum_j p[j] * v[h][j]; p from rowh.
        // Two 4-head halves keep only acc[4] live (was acc[8]).
        #pragma unroll
        for (int hh = 0; hh < 2; ++hh) {
            float acc[4];
            #pragma unroll
            for (int h4 = 0; h4 < 4; ++h4) {
                const int h = hh * 4 + h4;
                float a0 = 0.0f, a1 = 0.0f;
                #pragma unroll
                for (int jc = 0; jc < 8; ++jc) {
                    uqu u;
                    u.h8 = *(const half8*)&bufA[t * TOKPAD + h * 32 + jc * 4];
                    h2u q0, q1, q2, q3;
                    q0.u = rowh[jc * 4 + 0];
                    q1.u = rowh[jc * 4 + 1];
                    q2.u = rowh[jc * 4 + 2];
                    q3.u = rowh[jc * 4 + 3];
                    a0 = dot2(q0.h, u.h2[0], a0);
                    a1 = dot2(q1.h, u.h2[1], a1);
                    a0 = dot2(q2.h, u.h2[2], a0);
                    a1 = dot2(q3.h, u.h2[3], a1);
                }
                acc[h4] = a0 + a1;
            }
            #pragma unroll
            for (int h4 = 0; h4 < 4; ++h4)
                resL[t * 520 + (hh * 4 + h4) * 64 + lane] = (__fp16)(acc[h4] * inv_sum);
        }
    }
    __syncthreads();   // #4: all 16 tokens' res in LDS -> out phase

    // ---- out phase: wave w computes out cols w*16..w*16+15 for 16 tokens.
    {
        floatx4 oacc = (floatx4){0.f, 0.f, 0.f, 0.f};
        const __fp16* rrow = resL + (size_t)m * 520 + quad * 8;   // token m
        const __fp16* wrow = wuh + (size_t)(w * 16 + m) * HHE + quad * 8;
        #pragma unroll
        for (int kc = 0; kc < 16; ++kc) {              // K=512 in 32-chunks
            const half8 bf = *(const half8*)(rrow + kc * 32);
            const half8 af = *(const half8*)(wrow + kc * 32);
            oacc = __builtin_amdgcn_mfma_f32_16x16x32_f16(af, bf, oacc, 0, 0, 0);
        }
        const int tok = tok0 + m;
        const int col = w * 16 + quad * 4;             // 4 consecutive out cols
        const float4 b4 = *(const float4*)&bu[col];
        float4 o;
        o.x = oacc[0] + b4.x;
        o.y = oacc[1] + b4.y;
        o.z = oacc[2] + b4.z;
        o.w = oacc[3] + b4.w;
        *(float4*)&out[(size_t)tok * 64 + col] = o;
    }
}

// ---------------------------------------------------------------------------
extern "C" void kernel_launch(void* const* d_in, const int* in_sizes, int n_in,
                              void* d_out, int out_size, void* d_ws, size_t ws_size,
                              hipStream_t stream)
{
    const float* x     = (const float*)d_in[0];
    const float* alpha = (const float*)d_in[1];
    const float* Wk    = (const float*)d_in[2];
    const float* bk    = (const float*)d_in[3];
    const float* Wq    = (const float*)d_in[4];
    const float* bq    = (const float*)d_in[5];
    const float* Wv    = (const float*)d_in[6];
    const float* bv    = (const float*)d_in[7];
    const float* Wu    = (const float*)d_in[8];
    const float* bu    = (const float*)d_in[9];
    float* out = (float*)d_out;

    // workspace (fp16 units): wkh/wqh/wvh/wuh 32768 each
    __fp16* wkh  = (__fp16*)d_ws;
    __fp16* wqh  = wkh + (size_t)HHE * EDIM;
    __fp16* wvh  = wqh + (size_t)HHE * EDIM;
    __fp16* wuh  = wvh + (size_t)HHE * EDIM;

    cvt_fp16_kernel<<<dim3(16, 4), 256, 0, stream>>>(
        Wk, Wq, Wv, Wu, wkh, wqh, wvh, wuh, alpha);
    qkv_attn_out_kernel<<<NTOK / TPB, 256, 0, stream>>>(
        x, wkh, bk, wqh, bq, wvh, bv, wuh, bu, out, alpha);
}

// Round 20
// 143.781 us; speedup vs baseline: 1.0161x; 1.0161x over previous
//
#include <hip/hip_runtime.h>
#include <math.h>

// Problem constants (b=8, c=2048, e=64, h=8)
#define NTOK 16384
#define EDIM 64
#define HHE  512   // h*e
#define TPB  16    // tokens per block
#define TOKPAD 260 // half2 slots per token row: 256 + 4 pad (16B-aligned rows)

typedef _Float16 half8 __attribute__((ext_vector_type(8)));   // MFMA operand type
typedef __fp16   half2v __attribute__((ext_vector_type(2)));  // builtin V2h type
typedef _Float16 f16x2 __attribute__((ext_vector_type(2)));
typedef float    floatx4 __attribute__((ext_vector_type(4)));

__device__ __forceinline__ half8 cvt8(const float4 a, const float4 b) {
    half8 h;
    h[0] = (_Float16)a.x; h[1] = (_Float16)a.y;
    h[2] = (_Float16)a.z; h[3] = (_Float16)a.w;
    h[4] = (_Float16)b.x; h[5] = (_Float16)b.y;
    h[6] = (_Float16)b.z; h[7] = (_Float16)b.w;
    return h;
}

// fp32 += half2 . half2 (v_dot2_f32_f16)
__device__ __forceinline__ float dot2(half2v a, half2v b, float c) {
#if __has_builtin(__builtin_amdgcn_fdot2)
    return __builtin_amdgcn_fdot2(a, b, c, false);
#else
    return fmaf((float)a[0], (float)b[0], fmaf((float)a[1], (float)b[1], c));
#endif
}
__device__ __forceinline__ half2v pk(float x, float y) {
    return __builtin_amdgcn_cvt_pkrtz(x, y);   // v_cvt_pkrtz_f16_f32 (V2h)
}
union h2u { half2v h; f16x2 f; unsigned int u; };
union uqu { half8 h8; half2v h2[4]; };

// ---- FORCED packed-fp16 VOP3P ops on 32-bit pair registers (inline asm;
// hipcc does not form these from vector types — proven R21/R22 counters).
__device__ __forceinline__ unsigned pka16(unsigned a, unsigned b) {
    unsigned d;
    asm("v_pk_add_f16 %0, %1, %2" : "=v"(d) : "v"(a), "v"(b));
    return d;
}
__device__ __forceinline__ unsigned pkmax16(unsigned a, unsigned b) {
    unsigned d;
    asm("v_pk_max_f16 %0, %1, %2" : "=v"(d) : "v"(a), "v"(b));
    return d;
}
__device__ __forceinline__ unsigned pkmul16(unsigned a, unsigned b) {
    unsigned d;
    asm("v_pk_mul_f16 %0, %1, %2" : "=v"(d) : "v"(a), "v"(b));
    return d;
}
__device__ __forceinline__ unsigned pkrelu16(unsigned x, unsigned z0) {
    return pkmax16(x, z0);   // clamp pair to [0,inf); 0u = +0|+0 fp16 pair
}
__device__ __forceinline__ float dot2u(unsigned a, unsigned b, float c) {
    h2u ua, ub; ua.u = a; ub.u = b;
    return dot2(ua.h, ub.h, c);
}

__device__ __forceinline__ float pgen(float z, float inv) {
    return z > 0.0f ? exp2f(inv * log2f(fmaxf(z, 1e-30f))) : 0.0f;
}

// ---------------------------------------------------------------------------
// Kernel 0: fp32 -> fp16 (RTN cast) for the 4 weight matrices only.
// Wq pre-scaled by (alpha-1)/sqrt(e) so the score scale vanishes downstream.
// ---------------------------------------------------------------------------
__global__ __launch_bounds__(256) void cvt_fp16_kernel(
    const float* __restrict__ Wk, const float* __restrict__ Wq,
    const float* __restrict__ Wv, const float* __restrict__ Wu,
    __fp16* __restrict__ wkh, __fp16* __restrict__ wqh,
    __fp16* __restrict__ wvh, __fp16* __restrict__ wuh,
    const float* alpha_p)
{
    const int z = blockIdx.y;
    const float* src; __fp16* dst;
    float s = 1.0f;
    if      (z == 0) { src = Wk; dst = wkh; }
    else if (z == 1) { src = Wq; dst = wqh; s = (alpha_p[0] - 1.0f) * 0.125f; }
    else if (z == 2) { src = Wv; dst = wvh; }
    else             { src = Wu; dst = wuh; }
    const int idx = (blockIdx.x * 256 + threadIdx.x) * 8;
    float4 a = *(const float4*)(src + idx);
    float4 b = *(const float4*)(src + idx + 4);
    a.x *= s; a.y *= s; a.z *= s; a.w *= s;
    b.x *= s; b.y *= s; b.z *= s; b.w *= s;
    *(half8*)(dst + idx) = cvt8(a, b);
}

// ---------------------------------------------------------------------------
// Kernel 1: FULLY FUSED qkv + entmax-attention + output projection.
// R29: kill the union-ARRAY. R26/R27/R28 proved the ~16-dword/thread
// scratch traffic (WRITE 20.5MB, FETCH 11.5MB) is IMMUNE to launch
// bounds (cap 128 / cap 170 / none -> identical binaries): it is not
// register-pressure spill but an unpromoted alloca — uqu uqAll[4], an
// array of type-punned unions held across phase B (classic SROA
// failure; R23's transient per-iteration union was clean). Fix: four
// NAMED uqu variables + macro-expanded consumer body (no array, no
// runtime indexing, no call). Everything else identical to R28.
// ---------------------------------------------------------------------------

// Consumer body for one token T with q-fragment UQ (named var, never an
// array element). Textual expansion guarantees register residency.
#define CONSUME_TOKEN(T, UQ)                                                   \
  do {                                                                         \
    const int t = (T);                                                         \
    float inv_sum;                                                             \
    unsigned rowh[32];                                                         \
    if (am1 == 0.5f) {                                                         \
      unsigned runmax = 0u;                                                    \
      _Pragma("unroll")                                                        \
      for (int j = 0; j < 64; j += 2) {                                        \
        uqu u0, u1;                                                            \
        u0.h8 = *(const half8*)&kT[t * TOKPAD + j * 4];                        \
        u1.h8 = *(const half8*)&kT[t * TOKPAD + (j + 1) * 4];                  \
        float d0 = dot2(UQ.h2[0], u0.h2[0], 0.0f);                             \
        float d1 = dot2(UQ.h2[0], u1.h2[0], 0.0f);                             \
        d0 = dot2(UQ.h2[1], u0.h2[1], d0);                                     \
        d1 = dot2(UQ.h2[1], u1.h2[1], d1);                                     \
        d0 = dot2(UQ.h2[2], u0.h2[2], d0);                                     \
        d1 = dot2(UQ.h2[2], u1.h2[2], d1);                                     \
        d0 = dot2(UQ.h2[3], u0.h2[3], d0);                                     \
        d1 = dot2(UQ.h2[3], u1.h2[3], d1);                                     \
        h2u c; c.h = pk(d0, d1);                                               \
        rowh[j >> 1] = c.u;                                                    \
        runmax = (j == 0) ? c.u : pkmax16(runmax, c.u);                        \
      }                                                                        \
      h2u mu; mu.u = runmax;                                                   \
      const float mx = fmaxf((float)mu.f[0], (float)mu.f[1]);                  \
      float tau_lo = mx - 1.0f;                                                \
      float dm = 1.0f - exp2f(-6.0f * am1);                                    \
      const unsigned z0 = 0u;                                                  \
      const half2v one2 = pk(1.0f, 1.0f);                                      \
      _Pragma("unroll")                                                        \
      for (int it = 0; it < 6; ++it) {                                         \
        dm *= 0.5f;                                                            \
        const float tau_m = tau_lo + dm;                                       \
        h2u ntc; ntc.h = pk(-tau_m, -tau_m);                                   \
        const unsigned nt = ntc.u;                                             \
        float f0 = -1.0f, f1 = 0.0f, f2 = 0.0f, f3 = 0.0f;                     \
        _Pragma("unroll")                                                      \
        for (int jj = 0; jj < 32; jj += 4) {                                   \
          const unsigned a0 = pkrelu16(pka16(rowh[jj + 0], nt), z0);           \
          const unsigned a1 = pkrelu16(pka16(rowh[jj + 1], nt), z0);           \
          const unsigned a2 = pkrelu16(pka16(rowh[jj + 2], nt), z0);           \
          const unsigned a3 = pkrelu16(pka16(rowh[jj + 3], nt), z0);           \
          f0 = dot2u(a0, a0, f0);                                              \
          f1 = dot2u(a1, a1, f1);                                              \
          f2 = dot2u(a2, a2, f2);                                              \
          f3 = dot2u(a3, a3, f3);                                              \
        }                                                                      \
        const float f = (f0 + f1) + (f2 + f3);                                 \
        tau_lo = (f >= 0.0f) ? tau_m : tau_lo;                                 \
      }                                                                        \
      float tau = tau_lo;                                                      \
      _Pragma("unroll")                                                        \
      for (int it = 0; it < 2; ++it) {                                         \
        h2u ntc; ntc.h = pk(-tau, -tau);                                       \
        const unsigned nt = ntc.u;                                             \
        float f0 = -1.0f, f1 = 0.0f;                                           \
        float s0 = 0.0f, s1 = 0.0f;                                            \
        _Pragma("unroll")                                                      \
        for (int jj = 0; jj < 32; jj += 2) {                                   \
          const unsigned a0 = pkrelu16(pka16(rowh[jj + 0], nt), z0);           \
          const unsigned a1 = pkrelu16(pka16(rowh[jj + 1], nt), z0);           \
          f0 = dot2u(a0, a0, f0);                                              \
          f1 = dot2u(a1, a1, f1);                                              \
          h2u ua0, ua1; ua0.u = a0; ua1.u = a1;                                \
          s0 = dot2(ua0.h, one2, s0);                                          \
          s1 = dot2(ua1.h, one2, s1);                                          \
        }                                                                      \
        const float f = f0 + f1;                                               \
        const float s = (s0 + s1) + 1e-20f;                                    \
        tau = tau + fmaxf(f, 0.0f) * __builtin_amdgcn_rcpf(s + s);             \
      }                                                                        \
      {                                                                        \
        h2u ntc; ntc.h = pk(-tau, -tau);                                       \
        const unsigned nt = ntc.u;                                             \
        float s0 = 0.0f, s1 = 0.0f;                                            \
        _Pragma("unroll")                                                      \
        for (int jj = 0; jj < 32; jj += 2) {                                   \
          const unsigned a0 = pkrelu16(pka16(rowh[jj + 0], nt), z0);           \
          const unsigned a1 = pkrelu16(pka16(rowh[jj + 1], nt), z0);           \
          s0 = dot2u(a0, a0, s0);                                              \
          s1 = dot2u(a1, a1, s1);                                              \
          rowh[jj + 0] = pkmul16(a0, a0);                                      \
          rowh[jj + 1] = pkmul16(a1, a1);                                      \
        }                                                                      \
        inv_sum = __builtin_amdgcn_rcpf(s0 + s1);                              \
      }                                                                        \
    } else {                                                                   \
      const float inv = 1.0f / am1;                                            \
      float mx = -3.4e38f;                                                     \
      for (int j = 0; j < 64; ++j) {                                           \
        uqu u0; u0.h8 = *(const half8*)&kT[t * TOKPAD + j * 4];                \
        float d = dot2(UQ.h2[0], u0.h2[0], 0.0f);                              \
        d = dot2(UQ.h2[1], u0.h2[1], d);                                       \
        d = dot2(UQ.h2[2], u0.h2[2], d);                                       \
        d = dot2(UQ.h2[3], u0.h2[3], d);                                       \
        mx = fmaxf(mx, d);                                                     \
      }                                                                        \
      float tau_lo = mx - 1.0f;                                                \
      float dm = (mx - exp2f(-6.0f * am1)) - tau_lo;                           \
      float f_lo = -1.0f;                                                      \
      for (int j = 0; j < 64; ++j) {                                           \
        uqu u0; u0.h8 = *(const half8*)&kT[t * TOKPAD + j * 4];                \
        float d = dot2(UQ.h2[0], u0.h2[0], 0.0f);                              \
        d = dot2(UQ.h2[1], u0.h2[1], d);                                       \
        d = dot2(UQ.h2[2], u0.h2[2], d);                                       \
        d = dot2(UQ.h2[3], u0.h2[3], d);                                       \
        f_lo += pgen(d - tau_lo, inv);                                         \
      }                                                                        \
      float tau_m = tau_lo;                                                    \
      for (int it = 0; it < 30; ++it) {                                        \
        dm *= 0.5f;                                                            \
        tau_m = tau_lo + dm;                                                   \
        float f = -1.0f;                                                       \
        for (int j = 0; j < 64; ++j) {                                         \
          uqu u0; u0.h8 = *(const half8*)&kT[t * TOKPAD + j * 4];              \
          float d = dot2(UQ.h2[0], u0.h2[0], 0.0f);                            \
          d = dot2(UQ.h2[1], u0.h2[1], d);                                     \
          d = dot2(UQ.h2[2], u0.h2[2], d);                                     \
          d = dot2(UQ.h2[3], u0.h2[3], d);                                     \
          f += pgen(d - tau_m, inv);                                           \
        }                                                                      \
        tau_lo = (f * f_lo >= 0.0f) ? tau_m : tau_lo;                          \
      }                                                                        \
      float s = 0.0f;                                                          \
      for (int j = 0; j < 64; j += 2) {                                        \
        uqu u0, u1;                                                            \
        u0.h8 = *(const half8*)&kT[t * TOKPAD + j * 4];                        \
        u1.h8 = *(const half8*)&kT[t * TOKPAD + (j + 1) * 4];                  \
        float d0 = dot2(UQ.h2[0], u0.h2[0], 0.0f);                             \
        float d1 = dot2(UQ.h2[0], u1.h2[0], 0.0f);                             \
        d0 = dot2(UQ.h2[1], u0.h2[1], d0);                                     \
        d1 = dot2(UQ.h2[1], u1.h2[1], d1);                                     \
        d0 = dot2(UQ.h2[2], u0.h2[2], d0);                                     \
        d1 = dot2(UQ.h2[2], u1.h2[2], d1);                                     \
        d0 = dot2(UQ.h2[3], u0.h2[3], d0);                                     \
        d1 = dot2(UQ.h2[3], u1.h2[3], d1);                                     \
        const float p0 = pgen(d0 - tau_m, inv);                                \
        const float p1 = pgen(d1 - tau_m, inv);                                \
        s += p0 + p1;                                                          \
        h2u c; c.h = pk(p0, p1);                                               \
        rowh[j >> 1] = c.u;                                                    \
      }                                                                        \
      inv_sum = 1.0f / s;                                                      \
    }                                                                          \
    _Pragma("unroll")                                                          \
    for (int hh = 0; hh < 2; ++hh) {                                           \
      float acc[4];                                                            \
      _Pragma("unroll")                                                        \
      for (int h4 = 0; h4 < 4; ++h4) {                                         \
        const int h = hh * 4 + h4;                                             \
        float a0 = 0.0f, a1 = 0.0f;                                            \
        _Pragma("unroll")                                                      \
        for (int jc = 0; jc < 8; ++jc) {                                       \
          uqu u;                                                               \
          u.h8 = *(const half8*)&bufA[t * TOKPAD + h * 32 + jc * 4];           \
          h2u q0, q1, q2, q3;                                                  \
          q0.u = rowh[jc * 4 + 0];                                             \
          q1.u = rowh[jc * 4 + 1];                                             \
          q2.u = rowh[jc * 4 + 2];                                             \
          q3.u = rowh[jc * 4 + 3];                                             \
          a0 = dot2(q0.h, u.h2[0], a0);                                        \
          a1 = dot2(q1.h, u.h2[1], a1);                                        \
          a0 = dot2(q2.h, u.h2[2], a0);                                        \
          a1 = dot2(q3.h, u.h2[3], a1);                                        \
        }                                                                      \
        acc[h4] = a0 + a1;                                                     \
      }                                                                        \
      _Pragma("unroll")                                                        \
      for (int h4 = 0; h4 < 4; ++h4)                                           \
        resL[t * 520 + (hh * 4 + h4) * 64 + lane] = (__fp16)(acc[h4] * inv_sum); \
    }                                                                          \
  } while (0)

__global__ __launch_bounds__(256) void qkv_attn_out_kernel(
    const float* __restrict__ x,
    const __fp16* __restrict__ wkh, const float* __restrict__ bk,
    const __fp16* __restrict__ wqh, const float* __restrict__ bq,
    const __fp16* __restrict__ wvh, const float* __restrict__ bv,
    const __fp16* __restrict__ wuh, const float* __restrict__ bu,
    float* __restrict__ out, const float* alpha_p)
{
    __shared__ __align__(16) half2v bufA[TPB * TOKPAD];  // q -> v overlay
    __shared__ __align__(16) half2v kT[TPB * TOKPAD];    // k -> res overlay

    const int tid  = threadIdx.x;
    const int lane = tid & 63;
    const int w    = tid >> 6;
    const int tok0 = blockIdx.x * TPB;

    const int m    = lane & 15;            // token (B row / MFMA D col)
    const int quad = lane >> 4;

    const float am1   = alpha_p[0] - 1.0f;
    const float s_q   = am1 * 0.125f;      // matches cvt kernel's Wq scale

    // ---- x B-fragments: fp32 load + RTN cast
    const float* xrow = x + (size_t)(tok0 + m) * EDIM + quad * 8;
    half8 bfr[2];
    {
        const float4 a0 = *(const float4*)(xrow);
        const float4 a1 = *(const float4*)(xrow + 4);
        const float4 a2 = *(const float4*)(xrow + 32);
        const float4 a3 = *(const float4*)(xrow + 36);
        bfr[0] = cvt8(a0, a1);
        bfr[1] = cvt8(a2, a3);
    }

    // ---- Phase A: produce k (units 0-3) and q (units 4-7); 2 units/wave.
    #pragma unroll
    for (int uu = 0; uu < 2; ++uu) {
        const int unit = w * 2 + uu;
        const int isq  = unit >> 2;            // 0 = k, 1 = q
        const int col0 = (unit & 3) * 128;
        const __fp16* W   = isq ? wqh : wkh;
        const float* bias = isq ? bq : bk;
        half2v* dstT      = isq ? bufA : kT;
        const float bs    = isq ? s_q : 1.0f;

        #pragma unroll
        for (int ct = 0; ct < 8; ++ct) {
            const int n = col0 + ct * 16 + m;
            const int grow = (n & 7) * 64 + (n >> 3);   // permuted W row (q/k)
            const __fp16* wrow = W + (size_t)grow * EDIM + quad * 8;
            floatx4 acc = (floatx4){0.f, 0.f, 0.f, 0.f};
            #pragma unroll
            for (int kc = 0; kc < 2; ++kc) {
                const half8 af = *(const half8*)(wrow + kc * 32);
                acc = __builtin_amdgcn_mfma_f32_16x16x32_f16(af, bfr[kc], acc, 0, 0, 0);
            }
            // lane's 4 regs = D rows quad*4+0..3, D col = m (token)
            // output rows g(n'): h = 4*(quad&1)+reg, j = col0/8+ct*2+(quad>>1)
            const int hbase = 4 * (quad & 1);
            const int j     = (col0 >> 3) + ct * 2 + (quad >> 1);
            float o0 = fmaf(bias[(hbase + 0) * 64 + j], bs, acc[0]);
            float o1 = fmaf(bias[(hbase + 1) * 64 + j], bs, acc[1]);
            float o2 = fmaf(bias[(hbase + 2) * 64 + j], bs, acc[2]);
            float o3 = fmaf(bias[(hbase + 3) * 64 + j], bs, acc[3]);
            h2u p0, p1;
            p0.h = pk(o0, o1);
            p1.h = pk(o2, o3);
            uint2 st; st.x = p0.u; st.y = p1.u;
            *(uint2*)&dstT[m * TOKPAD + j * 4 + 2 * (quad & 1)] = st;
        }
    }
    __syncthreads();   // #1: q,k fully written

    // ---- hoist this wave's 4 private q rows into NAMED registers
    // (no array of unions: R26-R28's scratch traffic was an unpromoted
    // alloca on uqAll[4], immune to launch-bound changes)
    uqu uq0, uq1, uq2, uq3;
    uq0.h8 = *(const half8*)&bufA[(w * 4 + 0) * TOKPAD + lane * 4];
    uq1.h8 = *(const half8*)&bufA[(w * 4 + 1) * TOKPAD + lane * 4];
    uq2.h8 = *(const half8*)&bufA[(w * 4 + 2) * TOKPAD + lane * 4];
    uq3.h8 = *(const half8*)&bufA[(w * 4 + 3) * TOKPAD + lane * 4];
    __syncthreads();   // #2: all q reads complete before v overwrites bufA

    // ---- Phase B: produce v into bufA; 1 unit/wave (col0 = w*128)
    {
        const int col0 = w * 128;
        #pragma unroll
        for (int ct = 0; ct < 8; ++ct) {
            const int n = col0 + ct * 16 + m;
            const __fp16* wrow = wvh + (size_t)n * EDIM + quad * 8;  // natural row
            floatx4 acc = (floatx4){0.f, 0.f, 0.f, 0.f};
            #pragma unroll
            for (int kc = 0; kc < 2; ++kc) {
                const half8 af = *(const half8*)(wrow + kc * 32);
                acc = __builtin_amdgcn_mfma_f32_16x16x32_f16(af, bfr[kc], acc, 0, 0, 0);
            }
            // natural: cols nn..nn+3 = v[h][jj..jj+3]
            const int nn = col0 + ct * 16 + quad * 4;
            const int h  = nn >> 6;
            const int jj = nn & 63;
            const float4 b4 = *(const float4*)&bv[nn];
            h2u p0, p1;
            p0.h = pk(acc[0] + b4.x, acc[1] + b4.y);
            p1.h = pk(acc[2] + b4.z, acc[3] + b4.w);
            uint2 st; st.x = p0.u; st.y = p1.u;
            *(uint2*)&bufA[m * TOKPAD + h * 32 + (jj >> 1)] = st;
        }
    }
    __syncthreads();   // #3: v ready

    __fp16* resL = (__fp16*)kT;            // res overlay: kT rows are wave-private

    // ---- consumer: 4 tokens, macro-expanded with named q fragments
    CONSUME_TOKEN(w * 4 + 0, uq0);
    CONSUME_TOKEN(w * 4 + 1, uq1);
    CONSUME_TOKEN(w * 4 + 2, uq2);
    CONSUME_TOKEN(w * 4 + 3, uq3);
    __syncthreads();   // #4: all 16 tokens' res in LDS -> out phase

    // ---- out phase: wave w computes out cols w*16..w*16+15 for 16 tokens.
    {
        floatx4 oacc = (floatx4){0.f, 0.f, 0.f, 0.f};
        const __fp16* rrow = resL + (size_t)m * 520 + quad * 8;   // token m
        const __fp16* wrow = wuh + (size_t)(w * 16 + m) * HHE + quad * 8;
        #pragma unroll
        for (int kc = 0; kc < 16; ++kc) {              // K=512 in 32-chunks
            const half8 bf = *(const half8*)(rrow + kc * 32);
            const half8 af = *(const half8*)(wrow + kc * 32);
            oacc = __builtin_amdgcn_mfma_f32_16x16x32_f16(af, bf, oacc, 0, 0, 0);
        }
        const int tok = tok0 + m;
        const int col = w * 16 + quad * 4;             // 4 consecutive out cols
        const float4 b4 = *(const float4*)&bu[col];
        float4 o;
        o.x = oacc[0] + b4.x;
        o.y = oacc[1] + b4.y;
        o.z = oacc[2] + b4.z;
        o.w = oacc[3] + b4.w;
        *(float4*)&out[(size_t)tok * 64 + col] = o;
    }
}

// ---------------------------------------------------------------------------
extern "C" void kernel_launch(void* const* d_in, const int* in_sizes, int n_in,
                              void* d_out, int out_size, void* d_ws, size_t ws_size,
                              hipStream_t stream)
{
    const float* x     = (const float*)d_in[0];
    const float* alpha = (const float*)d_in[1];
    const float* Wk    = (const float*)d_in[2];
    const float* bk    = (const float*)d_in[3];
    const float* Wq    = (const float*)d_in[4];
    const float* bq    = (const float*)d_in[5];
    const float* Wv    = (const float*)d_in[6];
    const float* bv    = (const float*)d_in[7];
    const float* Wu    = (const float*)d_in[8];
    const float* bu    = (const float*)d_in[9];
    float* out = (float*)d_out;

    // workspace (fp16 units): wkh/wqh/wvh/wuh 32768 each
    __fp16* wkh  = (__fp16*)d_ws;
    __fp16* wqh  = wkh + (size_t)HHE * EDIM;
    __fp16* wvh  = wqh + (size_t)HHE * EDIM;
    __fp16* wuh  = wvh + (size_t)HHE * EDIM;

    cvt_fp16_kernel<<<dim3(16, 4), 256, 0, stream>>>(
        Wk, Wq, Wv, Wu, wkh, wqh, wvh, wuh, alpha);
    qkv_attn_out_kernel<<<NTOK / TPB, 256, 0, stream>>>(
        x, wkh, bk, wqh, bq, wvh, bv, wuh, bu, out, alpha);
}